// Round 1
// baseline (2099.622 us; speedup 1.0000x reference)
//
#include <hip/hip_runtime.h>

#define NN 100000
#define NE 3200000
#define DIN 512
#define DHID 256
#define DOUT 64
#define KPROP 10

// ---------------- edge-index layout probe ----------------
// Reference dtype is int64 but JAX default x64-off usually yields int32 and
// the harness doc says "integer -> const int*". Detect at runtime: if the
// buffer is int64 (little-endian, values < 2^31), every odd int32 word of the
// first 512 pairs is zero. For int32 layout those words are random src ids
// in [0,1e5) -> P(all zero) ~ 1e-2560.
__global__ void detect_i64(const int* __restrict__ ei, int* __restrict__ flag) {
  if (blockIdx.x == 0 && threadIdx.x == 0) {
    int z = 1;
    for (int i = 0; i < 512; i++) if (ei[2*i + 1] != 0) { z = 0; break; }
    *flag = z;
  }
}

__device__ __forceinline__ int edge_at(const int* __restrict__ ei, int row, int e, int is64) {
  size_t base = (size_t)row * NE + (size_t)e;
  return is64 ? ei[base * 2] : ei[base];
}

// ---------------- degree / CSR build ----------------
__global__ void zero_cnt(int* __restrict__ cnt) {
  int g = blockIdx.x * blockDim.x + threadIdx.x;
  if (g < NN) cnt[g] = 0;
}

__global__ void count_deg(const int* __restrict__ ei, const int* __restrict__ flag,
                          int* __restrict__ cnt) {
  int g = blockIdx.x * blockDim.x + threadIdx.x;
  if (g < NE) {
    int d = edge_at(ei, 1, g, *flag);
    atomicAdd(&cnt[d], 1);
  }
}

__global__ void scan1(const int* __restrict__ cnt, int* __restrict__ rs,
                      int* __restrict__ bsum) {
  __shared__ int tmp[1024];
  int t = threadIdx.x;
  int g = blockIdx.x * 1024 + t;
  int v = (g < NN) ? cnt[g] : 0;
  tmp[t] = v;
  __syncthreads();
  for (int off = 1; off < 1024; off <<= 1) {
    int y = (t >= off) ? tmp[t - off] : 0;
    __syncthreads();
    tmp[t] += y;
    __syncthreads();
  }
  if (g < NN) rs[g] = tmp[t] - v;          // exclusive
  if (t == 1023) bsum[blockIdx.x] = tmp[t]; // block total
}

__global__ void scan2(int* __restrict__ bsum, int nb) {
  if (blockIdx.x == 0 && threadIdx.x == 0) {
    int s = 0;
    for (int i = 0; i < nb; i++) { int v = bsum[i]; bsum[i] = s; s += v; }
  }
}

__global__ void scan3_and_dis(int* __restrict__ rs, const int* __restrict__ bsum,
                              int* __restrict__ cursor, const int* __restrict__ cnt,
                              float* __restrict__ dis) {
  int g = blockIdx.x * blockDim.x + threadIdx.x;
  if (g < NN) {
    int v = rs[g] + bsum[g >> 10];
    rs[g] = v;
    cursor[g] = v;
    dis[g] = rsqrtf((float)(cnt[g] + 1)); // +1 self-loop; deg>=1 always
  }
}

__global__ void fill_csr(const int* __restrict__ ei, const int* __restrict__ flag,
                         const float* __restrict__ dis, int* __restrict__ cursor,
                         int* __restrict__ col, float* __restrict__ normv) {
  int g = blockIdx.x * blockDim.x + threadIdx.x;
  if (g < NE) {
    int is64 = *flag;
    int s = edge_at(ei, 0, g, is64);
    int d = edge_at(ei, 1, g, is64);
    int p = atomicAdd(&cursor[d], 1);
    col[p] = s;
    normv[p] = dis[s] * dis[d];
  }
}

// ---------------- fused MLP: h = relu(x@W1+b1)@W2+b2; out = temp[0]*h ------
// 16 nodes per block, 256 threads. Stage A: h1[16x256] via LDS-staged x tile;
// Stage B: h[16x64]. fp32 vector ALU (no fp32 MFMA on CDNA4).
__global__ __launch_bounds__(256) void mlp_fused(
    const float* __restrict__ x, const float* __restrict__ W1,
    const float* __restrict__ b1, const float* __restrict__ W2,
    const float* __restrict__ b2, const float* __restrict__ temp,
    float* __restrict__ h, float* __restrict__ out)
{
  __shared__ float xs[16][DIN];    // 32 KB
  __shared__ float h1s[16][DHID];  // 16 KB
  int t = threadIdx.x;
  int n0 = blockIdx.x * 16;

  // coalesced float4 load of x tile (16x512 f32 = 2048 float4)
  for (int m = t; m < 16 * (DIN / 4); m += 256) {
    int i = m >> 7;        // DIN/4 = 128 float4 per row
    int k4 = m & 127;
    *(float4*)&xs[i][k4 * 4] =
        *(const float4*)&x[(size_t)(n0 + i) * DIN + (size_t)k4 * 4];
  }
  __syncthreads();

  int jg = t & 63;   // stage A: cols jg*4..jg*4+3; stage B: output col jg
  int ig = t >> 6;   // node group: nodes ig*4..ig*4+3

  // ---- stage A: h1 = relu(x@W1 + b1) ----
  float4 bb = *(const float4*)&b1[jg * 4];
  float acc[4][4];
  #pragma unroll
  for (int i = 0; i < 4; i++) {
    acc[i][0] = bb.x; acc[i][1] = bb.y; acc[i][2] = bb.z; acc[i][3] = bb.w;
  }
  for (int k = 0; k < DIN; k += 4) {
    float xv[4][4];
    #pragma unroll
    for (int i = 0; i < 4; i++)
      *(float4*)xv[i] = *(const float4*)&xs[ig * 4 + i][k];
    #pragma unroll
    for (int kk = 0; kk < 4; kk++) {
      float4 wv = *(const float4*)&W1[(size_t)(k + kk) * DHID + jg * 4];
      #pragma unroll
      for (int i = 0; i < 4; i++) {
        acc[i][0] = fmaf(xv[i][kk], wv.x, acc[i][0]);
        acc[i][1] = fmaf(xv[i][kk], wv.y, acc[i][1]);
        acc[i][2] = fmaf(xv[i][kk], wv.z, acc[i][2]);
        acc[i][3] = fmaf(xv[i][kk], wv.w, acc[i][3]);
      }
    }
  }
  #pragma unroll
  for (int i = 0; i < 4; i++) {
    float4 v;
    v.x = fmaxf(acc[i][0], 0.f);
    v.y = fmaxf(acc[i][1], 0.f);
    v.z = fmaxf(acc[i][2], 0.f);
    v.w = fmaxf(acc[i][3], 0.f);
    *(float4*)&h1s[ig * 4 + i][jg * 4] = v;
  }
  __syncthreads();

  // ---- stage B: h = h1@W2 + b2 ----
  float acc2[4];
  float b2v = b2[jg];
  #pragma unroll
  for (int i = 0; i < 4; i++) acc2[i] = b2v;
  for (int k = 0; k < DHID; k += 4) {
    float hv[4][4];
    #pragma unroll
    for (int i = 0; i < 4; i++)
      *(float4*)hv[i] = *(const float4*)&h1s[ig * 4 + i][k];
    #pragma unroll
    for (int kk = 0; kk < 4; kk++) {
      float w2v = W2[(size_t)(k + kk) * DOUT + jg];
      #pragma unroll
      for (int i = 0; i < 4; i++) acc2[i] = fmaf(hv[i][kk], w2v, acc2[i]);
    }
  }
  float t0 = temp[0];
  #pragma unroll
  for (int i = 0; i < 4; i++) {
    size_t o = (size_t)(n0 + ig * 4 + i) * DOUT + jg;
    h[o] = acc2[i];
    out[o] = t0 * acc2[i];
  }
}

// ---------------- propagation: hk_next = Â hk; out += temp[k]*hk_next ------
// One wave per node, lane = feature (64 features). Gather-based, no atomics;
// each neighbor row read is one coalesced 256B wave load.
__global__ __launch_bounds__(256) void prop_step(
    const float* __restrict__ hk, float* __restrict__ hkn, float* __restrict__ out,
    const int* __restrict__ rs, const int* __restrict__ cnt,
    const int* __restrict__ col, const float* __restrict__ normv,
    const float* __restrict__ dis, const float* __restrict__ temp, int kidx)
{
  int w = blockIdx.x * 4 + (threadIdx.x >> 6);
  int lane = threadIdx.x & 63;
  if (w >= NN) return;
  float dd = dis[w];
  size_t rowoff = (size_t)w * DOUT + lane;
  float a = dd * dd * hk[rowoff]; // self-loop term: norm = dis[i]^2
  int beg = rs[w], n = cnt[w];
  const int* cp = col + beg;
  const float* vp = normv + beg;
  int e = 0;
  for (; e + 4 <= n; e += 4) {
    int s0 = cp[e + 0], s1 = cp[e + 1], s2 = cp[e + 2], s3 = cp[e + 3];
    float n0 = vp[e + 0], n1 = vp[e + 1], n2 = vp[e + 2], n3 = vp[e + 3];
    float h0 = hk[(size_t)s0 * DOUT + lane];
    float h1 = hk[(size_t)s1 * DOUT + lane];
    float h2 = hk[(size_t)s2 * DOUT + lane];
    float h3 = hk[(size_t)s3 * DOUT + lane];
    a = fmaf(n0, h0, a); a = fmaf(n1, h1, a);
    a = fmaf(n2, h2, a); a = fmaf(n3, h3, a);
  }
  for (; e < n; ++e) a = fmaf(vp[e], hk[(size_t)cp[e] * DOUT + lane], a);
  hkn[rowoff] = a;
  out[rowoff] += temp[kidx] * a;
}

// ---------------- launch ----------------
extern "C" void kernel_launch(void* const* d_in, const int* in_sizes, int n_in,
                              void* d_out, int out_size, void* d_ws, size_t ws_size,
                              hipStream_t stream) {
  const float* x    = (const float*)d_in[0];
  const int*   ei   = (const int*)d_in[1];
  const float* W1   = (const float*)d_in[2];
  const float* b1   = (const float*)d_in[3];
  const float* W2   = (const float*)d_in[4];
  const float* b2   = (const float*)d_in[5];
  const float* temp = (const float*)d_in[6];
  float* out = (float*)d_out;

  char* wsb = (char*)d_ws;
  size_t off = 0;
  auto carve = [&](size_t bytes) -> void* {
    void* p = wsb + off;
    off = (off + bytes + 255) & ~(size_t)255;
    return p;
  };
  int*   cnt    = (int*)carve((size_t)NN * 4);
  int*   rs     = (int*)carve((size_t)NN * 4);
  int*   cursor = (int*)carve((size_t)NN * 4);
  int*   bsum   = (int*)carve(128 * 4);
  int*   flag   = (int*)carve(256);
  float* dis    = (float*)carve((size_t)NN * 4);
  int*   col    = (int*)carve((size_t)NE * 4);
  float* nv     = (float*)carve((size_t)NE * 4);
  float* hk_a   = (float*)carve((size_t)NN * DOUT * 4);
  float* hk_b   = (float*)carve((size_t)NN * DOUT * 4);
  if (off > ws_size) return; // ~78.6 MB needed

  detect_i64<<<1, 64, 0, stream>>>(ei, flag);
  zero_cnt<<<(NN + 255) / 256, 256, 0, stream>>>(cnt);
  count_deg<<<(NE + 255) / 256, 256, 0, stream>>>(ei, flag, cnt);
  scan1<<<(NN + 1023) / 1024, 1024, 0, stream>>>(cnt, rs, bsum);
  scan2<<<1, 64, 0, stream>>>(bsum, (NN + 1023) / 1024);
  scan3_and_dis<<<(NN + 255) / 256, 256, 0, stream>>>(rs, bsum, cursor, cnt, dis);
  fill_csr<<<(NE + 255) / 256, 256, 0, stream>>>(ei, flag, dis, cursor, col, nv);

  mlp_fused<<<NN / 16, 256, 0, stream>>>(x, W1, b1, W2, b2, temp, hk_a, out);

  const float* cur = hk_a;
  float* nxt = hk_b;
  for (int k = 1; k <= KPROP; k++) {
    prop_step<<<(NN + 3) / 4, 256, 0, stream>>>(cur, nxt, out, rs, cnt, col, nv,
                                                dis, temp, k);
    const float* t2 = nxt;
    nxt = (float*)cur;
    cur = t2;
  }
}

// Round 2
// 1556.605 us; speedup vs baseline: 1.3488x; 1.3488x over previous
//
#include <hip/hip_runtime.h>

#define NN 100000
#define NE 3200000
#define DIN 512
#define DHID 256
#define DOUT 64
#define KPROP 10

typedef _Float16 f16;
typedef _Float16 f16x8 __attribute__((ext_vector_type(8)));
typedef _Float16 f16x4 __attribute__((ext_vector_type(4)));
typedef float f32x4 __attribute__((ext_vector_type(4)));

// ---------------- edge-index layout probe ----------------
__global__ void detect_i64(const int* __restrict__ ei, int* __restrict__ flag) {
  if (blockIdx.x == 0 && threadIdx.x == 0) {
    int z = 1;
    for (int i = 0; i < 512; i++) if (ei[2*i + 1] != 0) { z = 0; break; }
    *flag = z;
  }
}

__device__ __forceinline__ int edge_at(const int* __restrict__ ei, int row, int e, int is64) {
  size_t base = (size_t)row * NE + (size_t)e;
  return is64 ? ei[base * 2] : ei[base];
}

// ---------------- degree / CSR build ----------------
__global__ void zero_cnt(int* __restrict__ cnt) {
  int g = blockIdx.x * blockDim.x + threadIdx.x;
  if (g < NN) cnt[g] = 0;
}

__global__ void count_deg(const int* __restrict__ ei, const int* __restrict__ flag,
                          int* __restrict__ cnt) {
  int g = blockIdx.x * blockDim.x + threadIdx.x;
  if (g < NE) {
    int d = edge_at(ei, 1, g, *flag);
    atomicAdd(&cnt[d], 1);
  }
}

__global__ void scan1(const int* __restrict__ cnt, int* __restrict__ rs,
                      int* __restrict__ bsum) {
  __shared__ int tmp[1024];
  int t = threadIdx.x;
  int g = blockIdx.x * 1024 + t;
  int v = (g < NN) ? cnt[g] : 0;
  tmp[t] = v;
  __syncthreads();
  for (int off = 1; off < 1024; off <<= 1) {
    int y = (t >= off) ? tmp[t - off] : 0;
    __syncthreads();
    tmp[t] += y;
    __syncthreads();
  }
  if (g < NN) rs[g] = tmp[t] - v;           // exclusive
  if (t == 1023) bsum[blockIdx.x] = tmp[t]; // block total
}

__global__ void scan2(int* __restrict__ bsum, int nb) {
  if (blockIdx.x == 0 && threadIdx.x == 0) {
    int s = 0;
    for (int i = 0; i < nb; i++) { int v = bsum[i]; bsum[i] = s; s += v; }
  }
}

__global__ void scan3_and_dis(int* __restrict__ rs, const int* __restrict__ bsum,
                              int* __restrict__ cursor, const int* __restrict__ cnt,
                              float* __restrict__ dis) {
  int g = blockIdx.x * blockDim.x + threadIdx.x;
  if (g < NN) {
    int v = rs[g] + bsum[g >> 10];
    rs[g] = v;
    cursor[g] = v;
    dis[g] = rsqrtf((float)(cnt[g] + 1)); // +1 self-loop
  }
}

__global__ void fill_csr(const int* __restrict__ ei, const int* __restrict__ flag,
                         const float* __restrict__ dis, int* __restrict__ cursor,
                         int* __restrict__ col, float* __restrict__ normv) {
  int g = blockIdx.x * blockDim.x + threadIdx.x;
  if (g < NE) {
    int is64 = *flag;
    int s = edge_at(ei, 0, g, is64);
    int d = edge_at(ei, 1, g, is64);
    int p = atomicAdd(&cursor[d], 1);
    col[p] = s;
    normv[p] = dis[s] * dis[d];
  }
}

// ---------------- weight transpose + fp16 convert ----------------
// W1 [512][256] -> W1t [256][512] f16 ; W2 [256][64] -> W2t [64][256] f16
__global__ void cvt_weights(const float* __restrict__ W1, const float* __restrict__ W2,
                            f16* __restrict__ W1t, f16* __restrict__ W2t) {
  int g = blockIdx.x * 256 + threadIdx.x;
  if (g < DIN * DHID) {
    int k = g >> 8, n = g & 255;
    W1t[(size_t)n * DIN + k] = (f16)W1[g];
  }
  if (g < DHID * DOUT) {
    int k = g >> 6, n = g & 63;
    W2t[(size_t)n * DHID + k] = (f16)W2[g];
  }
}

// ---------------- fused MLP via f16 MFMA ----------------
// 64 nodes/block, 256 threads (4 waves). GEMM1: M=64,N=256 (wave owns 64 cols),
// K=512 staged 128 at a time fp32->f16 in LDS. GEMM2: M=64 (wave owns 16 rows),
// N=64, K=256 from LDS h1. fp32 accum throughout.
__global__ __launch_bounds__(256) void mlp_mfma(
    const float* __restrict__ x, const f16* __restrict__ W1t,
    const float* __restrict__ b1, const f16* __restrict__ W2t,
    const float* __restrict__ b2, const float* __restrict__ temp,
    f16* __restrict__ h, float* __restrict__ out)
{
  __shared__ f16 xs[64][136];   // 17.0 KB (pad 8 to break bank stride)
  __shared__ f16 h1s[64][264];  // 33.0 KB
  int t = threadIdx.x;
  int lane = t & 63;
  int w = t >> 6;
  int n0 = blockIdx.x * 64;
  int r15 = lane & 15;
  int g4 = lane >> 4;
  int nbase = w * 64;

  f32x4 acc[4][4];
  #pragma unroll
  for (int nt = 0; nt < 4; nt++) {
    float bv = b1[nbase + nt * 16 + r15];
    #pragma unroll
    for (int mt = 0; mt < 4; mt++) acc[mt][nt] = (f32x4){bv, bv, bv, bv};
  }

  for (int k0 = 0; k0 < DIN; k0 += 128) {
    if (k0) __syncthreads();
    // stage x[64][128] fp32 -> f16 (coalesced float4 loads)
    #pragma unroll
    for (int it = 0; it < 8; it++) {
      int m = t + it * 256;          // over 64 rows x 32 float4
      int row = m >> 5, c4 = m & 31;
      int gr = n0 + row;
      float4 v = (gr < NN) ? *(const float4*)&x[(size_t)gr * DIN + k0 + c4 * 4]
                           : make_float4(0.f, 0.f, 0.f, 0.f);
      f16x4 hv = { (f16)v.x, (f16)v.y, (f16)v.z, (f16)v.w };
      *(f16x4*)&xs[row][c4 * 4] = hv;
    }
    __syncthreads();
    #pragma unroll
    for (int ks = 0; ks < 4; ks++) {
      int kk = ks * 32 + g4 * 8;
      f16x8 a[4], b[4];
      #pragma unroll
      for (int mt = 0; mt < 4; mt++)
        a[mt] = *(const f16x8*)&xs[mt * 16 + r15][kk];
      #pragma unroll
      for (int nt = 0; nt < 4; nt++)
        b[nt] = *(const f16x8*)&W1t[(size_t)(nbase + nt * 16 + r15) * DIN + k0 + kk];
      #pragma unroll
      for (int mt = 0; mt < 4; mt++)
        #pragma unroll
        for (int nt = 0; nt < 4; nt++)
          acc[mt][nt] = __builtin_amdgcn_mfma_f32_16x16x32_f16(a[mt], b[nt], acc[mt][nt], 0, 0, 0);
    }
  }
  // relu -> h1s f16 (D layout: col = lane&15, row = g4*4+reg  [m89-verified])
  #pragma unroll
  for (int mt = 0; mt < 4; mt++)
    #pragma unroll
    for (int nt = 0; nt < 4; nt++)
      #pragma unroll
      for (int r = 0; r < 4; r++) {
        float v = fmaxf(acc[mt][nt][r], 0.f);
        h1s[mt * 16 + g4 * 4 + r][nbase + nt * 16 + r15] = (f16)v;
      }
  __syncthreads();

  // GEMM2: wave w -> rows w*16..w*16+15, cols 0..63
  f32x4 acc2[4];
  #pragma unroll
  for (int nt = 0; nt < 4; nt++) {
    float bv = b2[nt * 16 + r15];
    acc2[nt] = (f32x4){bv, bv, bv, bv};
  }
  #pragma unroll
  for (int ks = 0; ks < 8; ks++) {
    int kk = ks * 32 + g4 * 8;
    f16x8 a2 = *(const f16x8*)&h1s[w * 16 + r15][kk];
    #pragma unroll
    for (int nt = 0; nt < 4; nt++) {
      f16x8 bf = *(const f16x8*)&W2t[(size_t)(nt * 16 + r15) * DHID + kk];
      acc2[nt] = __builtin_amdgcn_mfma_f32_16x16x32_f16(a2, bf, acc2[nt], 0, 0, 0);
    }
  }
  float t0 = temp[0];
  #pragma unroll
  for (int nt = 0; nt < 4; nt++)
    #pragma unroll
    for (int r = 0; r < 4; r++) {
      int node = n0 + w * 16 + g4 * 4 + r;
      if (node < NN) {
        int colv = nt * 16 + r15;
        float v = acc2[nt][r];
        h[(size_t)node * DOUT + colv] = (f16)v;
        out[(size_t)node * DOUT + colv] = t0 * v;
      }
    }
}

// ---------------- propagation (fp16 state): hk_next = A_hat hk -------------
// One wave per node, lane = feature. Gather rows are 128B (fp16) -> halves
// LLC traffic vs fp32. fp32 accumulate; out accumulated in fp32.
__global__ __launch_bounds__(256) void prop_step(
    const f16* __restrict__ hk, f16* __restrict__ hkn, float* __restrict__ out,
    const int* __restrict__ rs, const int* __restrict__ cnt,
    const int* __restrict__ col, const float* __restrict__ normv,
    const float* __restrict__ dis, const float* __restrict__ temp, int kidx)
{
  int w = blockIdx.x * 4 + (threadIdx.x >> 6);
  int lane = threadIdx.x & 63;
  if (w >= NN) return;
  float dd = dis[w];
  size_t rowoff = (size_t)w * DOUT + lane;
  float a = dd * dd * (float)hk[rowoff]; // self-loop: norm = dis[i]^2
  int beg = rs[w], n = cnt[w];
  const int* cp = col + beg;
  const float* vp = normv + beg;
  int e = 0;
  for (; e + 4 <= n; e += 4) {
    int s0 = cp[e + 0], s1 = cp[e + 1], s2 = cp[e + 2], s3 = cp[e + 3];
    float n0 = vp[e + 0], n1 = vp[e + 1], n2 = vp[e + 2], n3 = vp[e + 3];
    float h0 = (float)hk[(size_t)s0 * DOUT + lane];
    float h1 = (float)hk[(size_t)s1 * DOUT + lane];
    float h2 = (float)hk[(size_t)s2 * DOUT + lane];
    float h3 = (float)hk[(size_t)s3 * DOUT + lane];
    a = fmaf(n0, h0, a); a = fmaf(n1, h1, a);
    a = fmaf(n2, h2, a); a = fmaf(n3, h3, a);
  }
  for (; e < n; ++e) a = fmaf(vp[e], (float)hk[(size_t)cp[e] * DOUT + lane], a);
  hkn[rowoff] = (f16)a;
  out[rowoff] += temp[kidx] * a;
}

// ---------------- launch ----------------
extern "C" void kernel_launch(void* const* d_in, const int* in_sizes, int n_in,
                              void* d_out, int out_size, void* d_ws, size_t ws_size,
                              hipStream_t stream) {
  const float* x    = (const float*)d_in[0];
  const int*   ei   = (const int*)d_in[1];
  const float* W1   = (const float*)d_in[2];
  const float* b1   = (const float*)d_in[3];
  const float* W2   = (const float*)d_in[4];
  const float* b2   = (const float*)d_in[5];
  const float* temp = (const float*)d_in[6];
  float* out = (float*)d_out;

  char* wsb = (char*)d_ws;
  size_t off = 0;
  auto carve = [&](size_t bytes) -> void* {
    void* p = wsb + off;
    off = (off + bytes + 255) & ~(size_t)255;
    return p;
  };
  int*   cnt    = (int*)carve((size_t)NN * 4);
  int*   rs     = (int*)carve((size_t)NN * 4);
  int*   cursor = (int*)carve((size_t)NN * 4);
  int*   bsum   = (int*)carve(128 * 4);
  int*   flag   = (int*)carve(256);
  float* dis    = (float*)carve((size_t)NN * 4);
  int*   col    = (int*)carve((size_t)NE * 4);
  float* nv     = (float*)carve((size_t)NE * 4);
  f16*   W1t    = (f16*)carve((size_t)DHID * DIN * 2);
  f16*   W2t    = (f16*)carve((size_t)DOUT * DHID * 2);
  f16*   hk_a   = (f16*)carve((size_t)NN * DOUT * 2);
  f16*   hk_b   = (f16*)carve((size_t)NN * DOUT * 2);
  if (off > ws_size) return; // ~54 MB needed

  detect_i64<<<1, 64, 0, stream>>>(ei, flag);
  zero_cnt<<<(NN + 255) / 256, 256, 0, stream>>>(cnt);
  count_deg<<<(NE + 255) / 256, 256, 0, stream>>>(ei, flag, cnt);
  scan1<<<(NN + 1023) / 1024, 1024, 0, stream>>>(cnt, rs, bsum);
  scan2<<<1, 64, 0, stream>>>(bsum, (NN + 1023) / 1024);
  scan3_and_dis<<<(NN + 255) / 256, 256, 0, stream>>>(rs, bsum, cursor, cnt, dis);
  fill_csr<<<(NE + 255) / 256, 256, 0, stream>>>(ei, flag, dis, cursor, col, nv);

  cvt_weights<<<(DIN * DHID + 255) / 256, 256, 0, stream>>>(W1, W2, W1t, W2t);
  mlp_mfma<<<(NN + 63) / 64, 256, 0, stream>>>(x, W1t, b1, W2t, b2, temp, hk_a, out);

  const f16* cur = hk_a;
  f16* nxt = hk_b;
  for (int k = 1; k <= KPROP; k++) {
    prop_step<<<(NN + 3) / 4, 256, 0, stream>>>(cur, nxt, out, rs, cnt, col, nv,
                                                dis, temp, k);
    const f16* t2 = nxt;
    nxt = (f16*)cur;
    cur = t2;
  }
}